// Round 1
// baseline (247.780 us; speedup 1.0000x reference)
//
#include <hip/hip_runtime.h>

// Problem: YOLOv1 loss. 802816 rows x 30 f32, two tensors, scalar out.
// HBM-bound: 192.6 MB read => ~31 us floor at 6.3 TB/s.
// 3-kernel plan: K1 per-block stats, K2 scan/threshold, K3 boundary block.

#define ROWS 256
#define COLS 30
#define NB   3136              // 802816 / 256
#define RC   (ROWS * COLS)     // 7680 floats per block per tensor
#define RC4  (RC / 4)          // 1920 float4

// Per-row loss math (matches reference exactly, fp32).
__device__ __forceinline__ void row_compute(const float* __restrict__ P,
                                            const float* __restrict__ T,
                                            bool& coord, float& r, float& noo) {
    const float C = 1.0f / 7.0f;
    float conf = T[4];
    coord = (conf == 1.0f);          // targets[:, :, 4] is exactly 0.0 / 1.0
    noo = 0.0f;
    if (conf == 0.0f) {
        float d4 = P[4] - conf;      // t4 == 0 here
        float d9 = P[9] - T[9];
        noo = d4 * d4 + d9 * d9;
    }
    float t0 = T[0], t1 = T[1], t2 = T[2], t3 = T[3];
    // target box: tb = t^2, ta = tb[:2]*C - tb[2:], tbb = ta*C + tb[2:]
    float tb0 = t0 * t0, tb1 = t1 * t1, tb2 = t2 * t2, tb3 = t3 * t3;
    float tax = tb0 * C - tb2, tay = tb1 * C - tb3;
    float tbx = tax * C + tb2, tby = tay * C + tb3;
    float areaT = (tbx - tax) * (tby - tay);
    float iou0 = 0.0f, iou1 = 0.0f;
#pragma unroll
    for (int b = 0; b < 2; ++b) {
        float px = P[5 * b + 0], py = P[5 * b + 1];
        float pw = P[5 * b + 2], ph = P[5 * b + 3];
        float pax = px * C - pw, pay = py * C - ph;
        float pbx = pax * C + pw, pby = pay * C + ph;
        float ltx = fmaxf(pax, tax), lty = fmaxf(pay, tay);
        float rbx = fminf(pbx, tbx), rby = fminf(pby, tby);
        float wx = fmaxf(rbx - ltx, 0.0f), wy = fmaxf(rby - lty, 0.0f);
        float inter = wx * wy;
        float areaP = (pbx - pax) * (pby - pay);
        float iou = inter / (areaP + areaT - inter);
        if (b == 0) iou0 = iou; else iou1 = iou;
    }
    int idx = (iou1 > iou0) ? 1 : 0;         // argmax, first on ties
    int so = 5 * idx;
    float sx = P[so + 0], sy = P[so + 1], sw = P[so + 2], sh = P[so + 3];
    // class argmax over t[10:30], first occurrence on ties (strict >)
    float best = T[10]; int bi = 0;
#pragma unroll
    for (int j = 1; j < 20; ++j) {
        float v = T[10 + j];
        if (v > best) { best = v; bi = j; }
    }
    float pc = P[10 + bi];
    float d0 = sx - t0, d1 = sy - t1, d2 = sw - t2, d3 = sh - t3;
    float dc = pc - 1.0f;
    // center + xywh + conf_l + cls_l  (conf_l == cls_l => 2x)
    r = d0 * d0 + d1 * d1 + d2 * d2 + d3 * d3 + 2.0f * dc * dc;
}

// Coalesced float4 staging of one 256-row block of both tensors into LDS.
// Loads batched into registers first to maximize outstanding VMEM.
__device__ __forceinline__ void stage_block(const float* __restrict__ p,
                                            const float* __restrict__ t,
                                            float* lp, float* lt,
                                            int blockId, int tid) {
    const float4* p4 = (const float4*)(p + (size_t)blockId * RC);
    const float4* t4 = (const float4*)(t + (size_t)blockId * RC);
    float4* lp4 = (float4*)lp;
    float4* lt4 = (float4*)lt;
    float4 a[8], b[8];
#pragma unroll
    for (int it = 0; it < 7; ++it) a[it] = p4[tid + it * 256];
#pragma unroll
    for (int it = 0; it < 7; ++it) b[it] = t4[tid + it * 256];
    bool tail = (tid < (RC4 - 7 * 256));   // 128 remaining
    if (tail) { a[7] = p4[tid + 1792]; b[7] = t4[tid + 1792]; }
#pragma unroll
    for (int it = 0; it < 7; ++it) lp4[tid + it * 256] = a[it];
#pragma unroll
    for (int it = 0; it < 7; ++it) lt4[tid + it * 256] = b[it];
    if (tail) { lp4[tid + 1792] = a[7]; lt4[tid + 1792] = b[7]; }
    __syncthreads();
}

// K1: per-block {coord count, sum of coord r-terms, sum of noobj terms}
__global__ __launch_bounds__(256) void yolo_k1(const float* __restrict__ p,
                                               const float* __restrict__ t,
                                               int* __restrict__ cnt,
                                               float* __restrict__ sumR,
                                               float* __restrict__ noo) {
    __shared__ float lp[RC];
    __shared__ float lt[RC];
    __shared__ float wr[4], wn[4];
    __shared__ int wc[4];
    int tid = threadIdx.x;
    stage_block(p, t, lp, lt, blockIdx.x, tid);

    bool coord; float r, nt;
    row_compute(lp + tid * COLS, lt + tid * COLS, coord, r, nt);
    float rl = coord ? r : 0.0f;

    unsigned long long bal = __ballot(coord);
    int c = (int)__popcll(bal);
#pragma unroll
    for (int off = 32; off > 0; off >>= 1) {
        rl += __shfl_down(rl, off);
        nt += __shfl_down(nt, off);
    }
    int wave = tid >> 6, lane = tid & 63;
    if (lane == 0) { wr[wave] = rl; wn[wave] = nt; wc[wave] = c; }
    __syncthreads();
    if (tid == 0) {
        cnt[blockIdx.x]  = wc[0] + wc[1] + wc[2] + wc[3];
        sumR[blockIdx.x] = wr[0] + wr[1] + wr[2] + wr[3];
        noo[blockIdx.x]  = wn[0] + wn[1] + wn[2] + wn[3];
    }
}

// K2: totals + chunked scan of block counts; sum fully-included blocks,
// find the single boundary block b* and its quota k*.
__global__ __launch_bounds__(256) void yolo_k2(const int* __restrict__ cnt,
                                               const float* __restrict__ sumR,
                                               const float* __restrict__ noo,
                                               float* __restrict__ scal) {
    __shared__ int   s_i[256];
    __shared__ float s_f[256];
    __shared__ int   s_scan[256];
    __shared__ int   s_running;
    __shared__ int   sh_nhalf;
    __shared__ float sh_noo;
    __shared__ int   sh_bstar, sh_kstar;
    int tid = threadIdx.x;

    // phase 1: n_obj and total noobj
    int c = 0; float nf = 0.0f;
    for (int i = tid; i < NB; i += 256) { c += cnt[i]; nf += noo[i]; }
    s_i[tid] = c; s_f[tid] = nf;
    __syncthreads();
    for (int s = 128; s > 0; s >>= 1) {
        if (tid < s) { s_i[tid] += s_i[tid + s]; s_f[tid] += s_f[tid + s]; }
        __syncthreads();
    }
    if (tid == 0) {
        sh_nhalf = s_i[0] >> 1;     // n_obj // 2
        sh_noo = s_f[0];
        s_running = 0;
        sh_bstar = -1;
        sh_kstar = 0;
    }
    __syncthreads();
    int n_half = sh_nhalf;

    // phase 2: chunked inclusive scan over 3136 block counts
    float fullAcc = 0.0f;
    for (int chunk = 0; chunk < NB; chunk += 256) {
        int i = chunk + tid;
        int ci = (i < NB) ? cnt[i] : 0;
        s_scan[tid] = ci;
        __syncthreads();
        for (int off = 1; off < 256; off <<= 1) {
            int add = (tid >= off) ? s_scan[tid - off] : 0;
            __syncthreads();
            s_scan[tid] += add;
            __syncthreads();
        }
        int incl = s_scan[tid];
        int prefix = s_running + incl - ci;    // exclusive global prefix
        if (i < NB && ci > 0) {
            if (prefix + ci <= n_half) {
                fullAcc += sumR[i];            // whole block included
            } else if (prefix < n_half) {      // exactly one thread, ever
                sh_bstar = i;
                sh_kstar = n_half - prefix;    // first k* coord rows of b*
            }
        }
        __syncthreads();
        if (tid == 255) s_running += incl;
        __syncthreads();
    }

    s_f[tid] = fullAcc;
    __syncthreads();
    for (int s = 128; s > 0; s >>= 1) {
        if (tid < s) s_f[tid] += s_f[tid + s];
        __syncthreads();
    }
    if (tid == 0) {
        scal[0] = 5.0f * s_f[0] + 0.5f * sh_noo;   // base loss
        ((int*)scal)[1] = sh_bstar;
        ((int*)scal)[2] = sh_kstar;
    }
}

// K3: recompute only the boundary block's rows, intra-block rank, final sum.
__global__ __launch_bounds__(256) void yolo_k3(const float* __restrict__ p,
                                               const float* __restrict__ t,
                                               const float* __restrict__ scal,
                                               float* __restrict__ out) {
    __shared__ float lp[RC];
    __shared__ float lt[RC];
    __shared__ int   wcnt[4];
    __shared__ float pr[4];
    int tid = threadIdx.x;
    int bstar = ((const int*)scal)[1];
    int kstar = ((const int*)scal)[2];
    float base = scal[0];
    float total = 0.0f;
    if (bstar >= 0) {   // uniform branch
        stage_block(p, t, lp, lt, bstar, tid);
        bool coord; float r, nt;
        row_compute(lp + tid * COLS, lt + tid * COLS, coord, r, nt);
        unsigned long long bal = __ballot(coord);
        int wave = tid >> 6, lane = tid & 63;
        if (lane == 0) wcnt[wave] = (int)__popcll(bal);
        __syncthreads();
        int waveoff = 0;
        for (int wi = 0; wi < wave; ++wi) waveoff += wcnt[wi];
        unsigned long long below_incl =
            (lane == 63) ? bal : (bal & ((1ull << (lane + 1)) - 1ull));
        int rank = waveoff + (int)__popcll(below_incl);  // inclusive in-block rank
        float val = (coord && rank <= kstar) ? r : 0.0f;
#pragma unroll
        for (int off = 32; off > 0; off >>= 1) val += __shfl_down(val, off);
        if (lane == 0) pr[wave] = val;
        __syncthreads();
        if (tid == 0) total = pr[0] + pr[1] + pr[2] + pr[3];
    }
    if (tid == 0) out[0] = base + 5.0f * total;
}

extern "C" void kernel_launch(void* const* d_in, const int* in_sizes, int n_in,
                              void* d_out, int out_size, void* d_ws, size_t ws_size,
                              hipStream_t stream) {
    (void)in_sizes; (void)n_in; (void)out_size; (void)ws_size;
    const float* p = (const float*)d_in[0];   // predictions
    const float* t = (const float*)d_in[1];   // targets
    char* ws = (char*)d_ws;                   // need ~38 KB
    int*   cnt  = (int*)ws;
    float* sumR = (float*)(ws + (size_t)NB * 4);
    float* noo  = (float*)(ws + (size_t)NB * 8);
    float* scal = (float*)(ws + (size_t)NB * 12);
    float* out  = (float*)d_out;

    yolo_k1<<<NB, 256, 0, stream>>>(p, t, cnt, sumR, noo);
    yolo_k2<<<1, 256, 0, stream>>>(cnt, sumR, noo, scal);
    yolo_k3<<<1, 256, 0, stream>>>(p, t, scal, out);
}

// Round 2
// 232.226 us; speedup vs baseline: 1.0670x; 1.0670x over previous
//
#include <hip/hip_runtime.h>

// YOLOv1 loss: 802816 rows x 30 f32, two tensors, scalar out. HBM-bound:
// 192.6 MB read => ~31 us floor at 6.3 TB/s.
// R2: K1 = no-LDS direct-load (occupancy was capped at 2 blocks/CU by 60KB
// LDS; rows are 120B contiguous so L1 gives full line utilization without
// staging). K2 = merged scan+boundary fixup, single block, 2 barriers.

#define COLS 30
#define NB   3136              // 802816 / 256 rows per K1 block

// Per-row loss math (bit-exact vs reference; all indices constant after
// unroll so arrays stay in registers — pc tracked in-loop to avoid dynamic
// register indexing).
__device__ __forceinline__ void row_compute(const float* __restrict__ P,
                                            const float* __restrict__ T,
                                            bool& coord, float& r, float& noo) {
    const float C = 1.0f / 7.0f;
    float conf = T[4];
    coord = (conf == 1.0f);          // targets col 4 is exactly 0.0 / 1.0
    noo = 0.0f;
    if (conf == 0.0f) {
        float d4 = P[4] - conf;      // t4 == 0 here
        float d9 = P[9] - T[9];
        noo = d4 * d4 + d9 * d9;
    }
    float t0 = T[0], t1 = T[1], t2 = T[2], t3 = T[3];
    float tb0 = t0 * t0, tb1 = t1 * t1, tb2 = t2 * t2, tb3 = t3 * t3;
    float tax = tb0 * C - tb2, tay = tb1 * C - tb3;
    float tbx = tax * C + tb2, tby = tay * C + tb3;
    float areaT = (tbx - tax) * (tby - tay);
    float iou0 = 0.0f, iou1 = 0.0f;
#pragma unroll
    for (int b = 0; b < 2; ++b) {
        float px = P[5 * b + 0], py = P[5 * b + 1];
        float pw = P[5 * b + 2], ph = P[5 * b + 3];
        float pax = px * C - pw, pay = py * C - ph;
        float pbx = pax * C + pw, pby = pay * C + ph;
        float ltx = fmaxf(pax, tax), lty = fmaxf(pay, tay);
        float rbx = fminf(pbx, tbx), rby = fminf(pby, tby);
        float wx = fmaxf(rbx - ltx, 0.0f), wy = fmaxf(rby - lty, 0.0f);
        float inter = wx * wy;
        float areaP = (pbx - pax) * (pby - pay);
        float iou = inter / (areaP + areaT - inter);
        if (b == 0) iou0 = iou; else iou1 = iou;
    }
    int idx = (iou1 > iou0) ? 1 : 0;         // argmax, first on ties
    float sx = idx ? P[5] : P[0];
    float sy = idx ? P[6] : P[1];
    float sw = idx ? P[7] : P[2];
    float sh = idx ? P[8] : P[3];
    // class argmax over t[10:30] (strict > => first occurrence), track pc
    float best = T[10]; float pc = P[10];
#pragma unroll
    for (int j = 1; j < 20; ++j) {
        float v = T[10 + j];
        if (v > best) { best = v; pc = P[10 + j]; }
    }
    float d0 = sx - t0, d1 = sy - t1, d2 = sw - t2, d3 = sh - t3;
    float dc = pc - 1.0f;
    r = d0 * d0 + d1 * d1 + d2 * d2 + d3 * d3 + 2.0f * dc * dc;
}

// Direct per-thread row load: 15 float2 each (rows are 120 B, 8 B aligned).
__device__ __forceinline__ void load_row(const float* __restrict__ src,
                                         long row, float* dst) {
    const float2* s2 = (const float2*)(src + row * (long)COLS);
#pragma unroll
    for (int i = 0; i < 15; ++i) {
        float2 v = s2[i];
        dst[2 * i] = v.x; dst[2 * i + 1] = v.y;
    }
}

// K1: per-block {coord count, sum of coord r-terms, sum of noobj terms}
__global__ __launch_bounds__(256) void yolo_k1(const float* __restrict__ p,
                                               const float* __restrict__ t,
                                               int* __restrict__ cnt,
                                               float* __restrict__ sumR,
                                               float* __restrict__ noo) {
    __shared__ float wr[4], wn[4];
    __shared__ int wc[4];
    int tid = threadIdx.x;
    long row = (long)blockIdx.x * 256 + tid;
    float Pr[30], Tr[30];
    load_row(p, row, Pr);
    load_row(t, row, Tr);

    bool coord; float r, nt;
    row_compute(Pr, Tr, coord, r, nt);
    float rl = coord ? r : 0.0f;

    unsigned long long bal = __ballot(coord);
    int c = (int)__popcll(bal);
#pragma unroll
    for (int off = 32; off > 0; off >>= 1) {
        rl += __shfl_down(rl, off);
        nt += __shfl_down(nt, off);
    }
    int wave = tid >> 6, lane = tid & 63;
    if (lane == 0) { wr[wave] = rl; wn[wave] = nt; wc[wave] = c; }
    __syncthreads();
    if (tid == 0) {
        cnt[blockIdx.x]  = wc[0] + wc[1] + wc[2] + wc[3];
        sumR[blockIdx.x] = wr[0] + wr[1] + wr[2] + wr[3];
        noo[blockIdx.x]  = wn[0] + wn[1] + wn[2] + wn[3];
    }
}

// K2 (merged old K2+K3): single block.
//  Phase A: per-thread contiguous 13-block range; shfl scan for global
//  exclusive prefix; accumulate fully-included blocks' sumR; locate the one
//  boundary block b* and its quota k*.
//  Phase B: recompute b*'s 256 rows directly from global, intra-block rank
//  via ballot, add first k* coord rows. Write scalar.
__global__ __launch_bounds__(256) void yolo_k2(const int* __restrict__ cnt,
                                               const float* __restrict__ sumR,
                                               const float* __restrict__ noo,
                                               const float* __restrict__ p,
                                               const float* __restrict__ t,
                                               float* __restrict__ out) {
    __shared__ int   wsum[4];
    __shared__ float wf[4], wn2[4];
    __shared__ int   s_bstar, s_kstar;
    __shared__ float s_base;
    __shared__ int   s_wcnt[4];
    int tid = threadIdx.x;
    int lane = tid & 63, wave = tid >> 6;
    if (tid == 0) { s_bstar = -1; s_kstar = 0; }

    const int PER = 13;                 // 256*13 = 3328 >= 3136
    int start = tid * PER;
    int end = min(NB, start + PER);

    int cloc = 0; float nloc = 0.0f;
    for (int i = start; i < end; ++i) { cloc += cnt[i]; nloc += noo[i]; }

    // inclusive shfl scan of cloc within wave, then cross-wave offsets
    int incl = cloc;
#pragma unroll
    for (int off = 1; off < 64; off <<= 1) {
        int v = __shfl_up(incl, off);
        if (lane >= off) incl += v;
    }
    if (lane == 63) wsum[wave] = incl;
    __syncthreads();
    int woff = 0;
#pragma unroll
    for (int w = 0; w < 4; ++w) woff += (w < wave) ? wsum[w] : 0;
    int ex = woff + incl - cloc;        // exclusive global prefix of my range
    int n_obj = wsum[0] + wsum[1] + wsum[2] + wsum[3];
    int n_half = n_obj >> 1;

    // walk my range: full inclusion + boundary detection
    float acc = 0.0f;
    int running = ex;
    for (int i = start; i < end; ++i) {
        int ci = cnt[i];
        if (ci > 0) {
            if (running + ci <= n_half) {
                acc += sumR[i];
            } else if (running < n_half) {  // exactly one thread ever
                s_bstar = i;
                s_kstar = n_half - running;
            }
        }
        running += ci;
    }

    // reduce acc and nloc across 256 threads
#pragma unroll
    for (int off = 32; off > 0; off >>= 1) {
        acc  += __shfl_down(acc, off);
        nloc += __shfl_down(nloc, off);
    }
    if (lane == 0) { wf[wave] = acc; wn2[wave] = nloc; }
    __syncthreads();
    if (tid == 0)
        s_base = 5.0f * (wf[0] + wf[1] + wf[2] + wf[3])
               + 0.5f * (wn2[0] + wn2[1] + wn2[2] + wn2[3]);
    __syncthreads();

    // Phase B: boundary block fixup
    int bstar = s_bstar, kstar = s_kstar;
    float total = 0.0f;
    if (bstar >= 0) {                    // uniform branch
        long row = (long)bstar * 256 + tid;
        float Pr[30], Tr[30];
        load_row(p, row, Pr);
        load_row(t, row, Tr);
        bool coord; float r, nt;
        row_compute(Pr, Tr, coord, r, nt);
        unsigned long long bal = __ballot(coord);
        if (lane == 0) s_wcnt[wave] = (int)__popcll(bal);
        __syncthreads();
        int waveoff = 0;
#pragma unroll
        for (int w = 0; w < 4; ++w) waveoff += (w < wave) ? s_wcnt[w] : 0;
        unsigned long long below_incl =
            (lane == 63) ? bal : (bal & ((1ull << (lane + 1)) - 1ull));
        int rank = waveoff + (int)__popcll(below_incl);  // inclusive rank
        float val = (coord && rank <= kstar) ? r : 0.0f;
#pragma unroll
        for (int off = 32; off > 0; off >>= 1) val += __shfl_down(val, off);
        if (lane == 0) wf[wave] = val;
        __syncthreads();
        if (tid == 0) total = wf[0] + wf[1] + wf[2] + wf[3];
    }
    if (tid == 0) out[0] = s_base + 5.0f * total;
}

extern "C" void kernel_launch(void* const* d_in, const int* in_sizes, int n_in,
                              void* d_out, int out_size, void* d_ws, size_t ws_size,
                              hipStream_t stream) {
    (void)in_sizes; (void)n_in; (void)out_size; (void)ws_size;
    const float* p = (const float*)d_in[0];   // predictions
    const float* t = (const float*)d_in[1];   // targets
    char* ws = (char*)d_ws;                   // ~38 KB used
    int*   cnt  = (int*)ws;
    float* sumR = (float*)(ws + (size_t)NB * 4);
    float* noo  = (float*)(ws + (size_t)NB * 8);
    float* out  = (float*)d_out;

    yolo_k1<<<NB, 256, 0, stream>>>(p, t, cnt, sumR, noo);
    yolo_k2<<<1, 256, 0, stream>>>(cnt, sumR, noo, p, t, out);
}